// Round 10
// baseline (77.479 us; speedup 1.0000x reference)
//
#include <hip/hip_runtime.h>
#include <math.h>

#define IN_F  256
#define OUT_F 256
#define OTILE 64      // o per block; lane = o
#define BTILE 8       // b per block; 2 per wave
#define NTH   256

typedef _Float16 h2 __attribute__((ext_vector_type(2)));   // -> v_pk_* f16 ops

// out[b,o] = (1 + min_i((x-1)*pe)) * n0 + (-1 + max_i((x-1)*pe + 2*pe)) * n1
// pe = sigmoid(w0-w1); n0 = sigmoid(pw0-pw1); n1 = 1-n0.
// pe stored fp16 in 32KB swizzled LDS (4 blocks/CU); main math packed fp16:
// t = pk_fma(x, pe, -pe); u = pk_fma(2, pe, t); pk_min/pk_max accumulate.
__global__ __launch_bounds__(NTH, 4)
void den_kernel(const float* __restrict__ x,
                const float* __restrict__ pew,
                const float* __restrict__ pnw,
                float* __restrict__ out)
{
    __shared__ __align__(16) _Float16 pe_lds[OTILE * IN_F];   // 32 KB; row o at byte 512*o

    const int tid = threadIdx.x;
    const int b0  = blockIdx.x * BTILE;
    const int o0  = blockIdx.y * OTILE;

    // ---- stage pe = sigmoid -> fp16, swizzled: byte_in_row ^= (row&15)<<3 ----
    {
        const int r16 = tid >> 4;            // 0..15
        const int c   = tid & 15;            // 0..15 (16 consecutive float4 = 256B/16 lanes)
        for (int rg = 0; rg < 4; ++rg) {
            const int o  = rg * 16 + r16;    // 0..63
            const int sw = (o & 15) << 3;
            const float4* wp = reinterpret_cast<const float4*>(pew + (size_t)(o0 + o) * (IN_F * 2));
            char* rowp = reinterpret_cast<char*>(&pe_lds[o * IN_F]);
            #pragma unroll
            for (int k = 0; k < 8; ++k) {
                float4 w = wp[k * 16 + c];   // (w0_i, w1_i, w0_{i+1}, w1_{i+1})
                float pe0 = __builtin_amdgcn_rcpf(1.0f + __expf(w.y - w.x));
                float pe1 = __builtin_amdgcn_rcpf(1.0f + __expf(w.w - w.z));
                const int byteoff = (4 * (k * 16 + c)) ^ sw;   // 4B store stays 4B-aligned
                h2 pv; pv.x = (_Float16)pe0; pv.y = (_Float16)pe1;
                *reinterpret_cast<h2*>(rowp + byteoff) = pv;
            }
        }
    }
    __syncthreads();   // the only barrier

    const int lane = tid & 63;               // lane = o offset
    const int wid  = tid >> 6;               // 0..3
    const int bb0  = b0 + wid * 2;           // 2 b-rows per wave
    const char* rowp = reinterpret_cast<const char*>(&pe_lds[lane * IN_F]);
    const int sw = (lane & 15) << 3;

    const h2 two2 = {(_Float16)2.0f, (_Float16)2.0f};
    h2 mn[2], mx[2];
    #pragma unroll
    for (int j = 0; j < 2; ++j) {
        mn[j].x = mn[j].y = (_Float16)INFINITY;
        mx[j].x = mx[j].y = (_Float16)(-INFINITY);
    }

    const float* xr0 = x + (size_t)bb0 * IN_F;   // wave-uniform base

    // ---- main loop: 64 chunks of 4 i: 1 x 8B LDS read + per-j {16B x load, 10 pk ops} ----
    #pragma unroll 4
    for (int c = 0; c < 64; ++c) {
        h2 pA = *reinterpret_cast<const h2*>(rowp + ((8 * c) ^ sw));       // pe[i], pe[i+1]
        h2 pB = *reinterpret_cast<const h2*>(rowp + (((8 * c) ^ sw) + 4)); // pe[i+2], pe[i+3]
        #pragma unroll
        for (int j = 0; j < 2; ++j) {
            float4 xv = *reinterpret_cast<const float4*>(xr0 + j * IN_F + 4 * c);  // uniform addr
            h2 xA; xA.x = (_Float16)xv.x; xA.y = (_Float16)xv.y;
            h2 xB; xB.x = (_Float16)xv.z; xB.y = (_Float16)xv.w;
            h2 tA = __builtin_elementwise_fma(xA, pA, -pA);    // (x-1)*pe
            h2 tB = __builtin_elementwise_fma(xB, pB, -pB);
            h2 uA = __builtin_elementwise_fma(two2, pA, tA);   // t + 2*pe
            h2 uB = __builtin_elementwise_fma(two2, pB, tB);
            mn[j] = __builtin_elementwise_min(mn[j], __builtin_elementwise_min(tA, tB));
            mx[j] = __builtin_elementwise_max(mx[j], __builtin_elementwise_max(uA, uB));
        }
    }

    // ---- epilogue: node softmax + combine; coalesced b32 stores ----
    const int o = o0 + lane;
    float2 nw = *reinterpret_cast<const float2*>(pnw + 2 * (size_t)o);
    float n0 = __builtin_amdgcn_rcpf(1.0f + __expf(nw.y - nw.x));
    float n1 = 1.0f - n0;
    #pragma unroll
    for (int j = 0; j < 2; ++j) {
        float mnf = fminf((float)mn[j].x, (float)mn[j].y);
        float mxf = fmaxf((float)mx[j].x, (float)mx[j].y);
        out[(size_t)(bb0 + j) * OUT_F + o] = (mnf + 1.0f) * n0 + (mxf - 1.0f) * n1;
    }
}

extern "C" void kernel_launch(void* const* d_in, const int* in_sizes, int n_in,
                              void* d_out, int out_size, void* d_ws, size_t ws_size,
                              hipStream_t stream) {
    (void)d_ws; (void)ws_size; (void)n_in; (void)out_size;
    const float* x   = (const float*)d_in[0];
    const float* pew = (const float*)d_in[1];
    const float* pnw = (const float*)d_in[2];
    float* out = (float*)d_out;
    const int B = in_sizes[0] / IN_F;          // 2048
    dim3 grid(B / BTILE, OUT_F / OTILE);       // 256 x 4 = 1024 blocks (4/CU)
    den_kernel<<<grid, NTH, 0, stream>>>(x, pew, pnw, out);
}